// Round 12
// baseline (254.811 us; speedup 1.0000x reference)
//
#include <hip/hip_runtime.h>
#include <hip/hip_bf16.h>
#include <math.h>

#define NEXP 64
#define TOPK 8

__device__ __forceinline__ float4 bperm4(float4 v, int srcl) {
    float4 r;
    r.x = __shfl(v.x, srcl);
    r.y = __shfl(v.y, srcl);
    r.z = __shfl(v.z, srcl);
    r.w = __shfl(v.w, srcl);
    return r;
}

// 4 lanes per row, 16 rows per wave, 4 independent waves per block.
// No LDS tile, no barriers. Loads/passthrough-stores are perfectly
// coalesced (4 x 1KB per wave); row-quarter ownership is restored with an
// in-register bpermute transpose. Selection = Batcher sort-8 x2 + bitonic
// top-8 merges (r11), cross-lane via __shfl_xor masks 1/2.
__global__ __launch_bounds__(256) void topk_router_kernel(
    const float* __restrict__ logits,
    float* __restrict__ w_out,      // [N,8] weights
    float* __restrict__ id_out,     // [N,8] ids stored as float values
    float* __restrict__ l_out,      // [N,64] passthrough copy
    int nrows)
{
    const int lane = threadIdx.x & 63;
    const int wv   = threadIdx.x >> 6;
    const int q    = lane & 3;          // quarter of the row this lane owns
    const int rloc = lane >> 2;         // row within wave 0..15
    const int rowBase = (blockIdx.x * 4 + wv) * 16;
    const int row  = rowBase + rloc;

    const size_t waveChunkBase = (size_t)rowBase * (NEXP / 4);  // float4 units
    const size_t totalChunks   = (size_t)nrows * (NEXP / 4);

    const float4* __restrict__ src = (const float4*)logits;
    float4* __restrict__ dst       = (float4*)l_out;

    // ---- perfectly coalesced loads: instr k covers 1KB contiguous ----
    size_t g0 = waveChunkBase + 0 * 64 + lane;
    size_t g1 = waveChunkBase + 1 * 64 + lane;
    size_t g2 = waveChunkBase + 2 * 64 + lane;
    size_t g3 = waveChunkBase + 3 * 64 + lane;
    float4 z = make_float4(0.f, 0.f, 0.f, 0.f);
    float4 ld0 = (g0 < totalChunks) ? src[g0] : z;
    float4 ld1 = (g1 < totalChunks) ? src[g1] : z;
    float4 ld2 = (g2 < totalChunks) ? src[g2] : z;
    float4 ld3 = (g3 < totalChunks) ? src[g3] : z;

    // ---- perfectly coalesced passthrough stores (full sectors, no RMW) ----
    if (g0 < totalChunks) dst[g0] = ld0;
    if (g1 < totalChunks) dst[g1] = ld1;
    if (g2 < totalChunks) dst[g2] = ld2;
    if (g3 < totalChunks) dst[g3] = ld3;

    // ---- in-register transpose: lane d pulls its owned chunks 4d+s.
    // chunk 4d+s lives in load register k = d>>4 of source lane 4*(d&15)+s.
    // ALL 64 lanes participate (no early exit before this point).
    const int srclb = 4 * (lane & 15);
    const int kq    = lane >> 4;
    float4 a0, a1, a2, a3;
    {
        float4 own[4];
        #pragma unroll
        for (int s = 0; s < 4; ++s) {
            float4 t0 = bperm4(ld0, srclb + s);
            float4 t1 = bperm4(ld1, srclb + s);
            float4 t2 = bperm4(ld2, srclb + s);
            float4 t3 = bperm4(ld3, srclb + s);
            own[s] = (kq == 0) ? t0 : (kq == 1) ? t1 : (kq == 2) ? t2 : t3;
        }
        a0 = own[0]; a1 = own[1]; a2 = own[2]; a3 = own[3];
    }

    if (row >= nrows) return;           // whole 4-lane quads exit together

    const int base = q * 16;
    float e0 = a0.x,  e1 = a0.y,  e2 = a0.z,  e3 = a0.w;
    float e4 = a1.x,  e5 = a1.y,  e6 = a1.z,  e7 = a1.w;
    float e8 = a2.x,  e9 = a2.y,  e10 = a2.z, e11 = a2.w;
    float e12 = a3.x, e13 = a3.y, e14 = a3.z, e15 = a3.w;
    int i0 = base + 0,  i1 = base + 1,  i2 = base + 2,  i3 = base + 3;
    int i4 = base + 4,  i5 = base + 5,  i6 = base + 6,  i7 = base + 7;
    int i8 = base + 8,  i9 = base + 9,  i10 = base + 10, i11 = base + 11;
    int i12 = base + 12, i13 = base + 13, i14 = base + 14, i15 = base + 15;

    float rm = -INFINITY;    // max of all rejected elements

    // compare-exchange, descending, strict (> only): equal values never swap
#define CE(VA, IA, VB, IB)                                        \
    {                                                             \
        bool s_ = ((VB) > (VA));                                  \
        float tv_ = (VA); int ti_ = (IA);                         \
        VA = s_ ? (VB) : (VA); IA = s_ ? (IB) : (IA);             \
        VB = s_ ? tv_  : (VB); IB = s_ ? ti_  : (IB);             \
    }

    // Batcher odd-even merge sort for 8 (19 CE), descending
#define SORT8(V0,I0,V1,I1,V2,I2,V3,I3,V4,I4,V5,I5,V6,I6,V7,I7)        \
    CE(V0,I0,V1,I1) CE(V2,I2,V3,I3) CE(V4,I4,V5,I5) CE(V6,I6,V7,I7)   \
    CE(V0,I0,V2,I2) CE(V1,I1,V3,I3) CE(V4,I4,V6,I6) CE(V5,I5,V7,I7)   \
    CE(V1,I1,V2,I2) CE(V5,I5,V6,I6)                                   \
    CE(V0,I0,V4,I4) CE(V1,I1,V5,I5) CE(V2,I2,V6,I6) CE(V3,I3,V7,I7)   \
    CE(V2,I2,V4,I4) CE(V3,I3,V5,I5)                                   \
    CE(V1,I1,V2,I2) CE(V3,I3,V4,I4) CE(V5,I5,V6,I6)

    SORT8(e0,i0, e1,i1, e2,i2, e3,i3, e4,i4, e5,i5, e6,i6, e7,i7)
    SORT8(e8,i8, e9,i9, e10,i10, e11,i11, e12,i12, e13,i13, e14,i14, e15,i15)

    // winner/loser step: VA <- max(VA,VB), rm <- max(rm, loser)
#define MTOP(VA, IA, VB, IB)                                      \
    {                                                             \
        bool s_ = ((VB) > (VA));                                  \
        float lo_ = s_ ? (VA) : (VB);                             \
        VA = s_ ? (VB) : (VA); IA = s_ ? (IB) : (IA);             \
        rm = fmaxf(rm, lo_);                                      \
    }

    // bitonic clean of a descending-bitonic 8 (12 CE)
#define BITONIC8(V0,I0,V1,I1,V2,I2,V3,I3,V4,I4,V5,I5,V6,I6,V7,I7)     \
    CE(V0,I0,V4,I4) CE(V1,I1,V5,I5) CE(V2,I2,V6,I6) CE(V3,I3,V7,I7)   \
    CE(V0,I0,V2,I2) CE(V1,I1,V3,I3) CE(V4,I4,V6,I6) CE(V5,I5,V7,I7)   \
    CE(V0,I0,V1,I1) CE(V2,I2,V3,I3) CE(V4,I4,V5,I5) CE(V6,I6,V7,I7)

    // intra-lane: top-8 of two sorted-8 lists (bitonic merge)
    MTOP(e0,i0, e15,i15) MTOP(e1,i1, e14,i14)
    MTOP(e2,i2, e13,i13) MTOP(e3,i3, e12,i12)
    MTOP(e4,i4, e11,i11) MTOP(e5,i5, e10,i10)
    MTOP(e6,i6, e9,i9)   MTOP(e7,i7, e8,i8)
    BITONIC8(e0,i0, e1,i1, e2,i2, e3,i3, e4,i4, e5,i5, e6,i6, e7,i7)

    // cross-lane merge: partner's sorted-8 reversed feeds the bitonic merge
#define MERGE_LEVEL(MASK)                                                     \
    {                                                                         \
        float b0 = __shfl_xor(e0, MASK), b1 = __shfl_xor(e1, MASK);           \
        float b2 = __shfl_xor(e2, MASK), b3 = __shfl_xor(e3, MASK);           \
        float b4 = __shfl_xor(e4, MASK), b5 = __shfl_xor(e5, MASK);           \
        float b6 = __shfl_xor(e6, MASK), b7 = __shfl_xor(e7, MASK);           \
        int   j0 = __shfl_xor(i0, MASK), j1 = __shfl_xor(i1, MASK);           \
        int   j2 = __shfl_xor(i2, MASK), j3 = __shfl_xor(i3, MASK);           \
        int   j4 = __shfl_xor(i4, MASK), j5 = __shfl_xor(i5, MASK);           \
        int   j6 = __shfl_xor(i6, MASK), j7 = __shfl_xor(i7, MASK);           \
        float pr = __shfl_xor(rm, MASK);                                      \
        rm = fmaxf(rm, pr);                                                   \
        MTOP(e0,i0, b7,j7) MTOP(e1,i1, b6,j6)                                 \
        MTOP(e2,i2, b5,j5) MTOP(e3,i3, b4,j4)                                 \
        MTOP(e4,i4, b3,j3) MTOP(e5,i5, b2,j2)                                 \
        MTOP(e6,i6, b1,j1) MTOP(e7,i7, b0,j0)                                 \
        BITONIC8(e0,i0, e1,i1, e2,i2, e3,i3, e4,i4, e5,i5, e6,i6, e7,i7)      \
    }

    MERGE_LEVEL(1)
    MERGE_LEVEL(2)

    // ---- tie screen: any equality/near-tie involving a selected element or
    // the 8/9 boundary lands adjacent here (lists are sorted); gap<=T -> slow.
    const float T = 1e-6f;
    bool tie = ((e0 - e1) <= T) | ((e1 - e2) <= T) | ((e2 - e3) <= T) |
               ((e3 - e4) <= T) | ((e4 - e5) <= T) | ((e5 - e6) <= T) |
               ((e6 - e7) <= T) | ((e7 - rm) <= T);

    float ce0, ce1, ce2, ce3, ce4, ce5, ce6, ce7;
    int   o0, o1, o2, o3, o4, o5, o6, o7;

    if (__builtin_expect(!tie, 1)) {
        // fast path: no representable score tie possible
        ce0 = 1.0f;
        ce1 = __expf(e1 - e0); ce2 = __expf(e2 - e0);
        ce3 = __expf(e3 - e0); ce4 = __expf(e4 - e0);
        ce5 = __expf(e5 - e0); ce6 = __expf(e6 - e0);
        ce7 = __expf(e7 - e0);
        o0 = i0; o1 = i1; o2 = i2; o3 = i3;
        o4 = i4; o5 = i5; o6 = i6; o7 = i7;
    } else {
        // exact path (rare, exec-masked, deterministic per row): re-read the
        // row, depth-10 stable selection + correctly-rounded-exp tie order.
        const float* rowp = logits + (size_t)row * NEXP;
        float sv0 = -INFINITY, sv1 = -INFINITY, sv2 = -INFINITY, sv3 = -INFINITY;
        float sv4 = -INFINITY, sv5 = -INFINITY, sv6 = -INFINITY, sv7 = -INFINITY;
        float sv8 = -INFINITY, sv9 = -INFINITY;
        int   si0 = 0, si1 = 0, si2 = 0, si3 = 0, si4 = 0;
        int   si5 = 0, si6 = 0, si7 = 0, si8 = 0, si9 = 0;

#define SLOW_STAGE(TV, TI)                                \
    {                                                     \
        bool gt = (x > TV);                               \
        float nv = gt ? x  : TV;                          \
        float cv = gt ? TV : x;                           \
        int   ni = gt ? xi : TI;                          \
        int   ci = gt ? TI : xi;                          \
        TV = nv; x = cv; TI = ni; xi = ci;                \
    }

        #pragma unroll 1
        for (int e = 0; e < NEXP; ++e) {
            float x = rowp[e]; int xi = e;
            SLOW_STAGE(sv0, si0)
            SLOW_STAGE(sv1, si1)
            SLOW_STAGE(sv2, si2)
            SLOW_STAGE(sv3, si3)
            SLOW_STAGE(sv4, si4)
            SLOW_STAGE(sv5, si5)
            SLOW_STAGE(sv6, si6)
            SLOW_STAGE(sv7, si7)
            SLOW_STAGE(sv8, si8)
            SLOW_STAGE(sv9, si9)
        }

        double m = (double)sv0;
        float s0 = (float)exp((double)sv0 - m);
        float s1 = (float)exp((double)sv1 - m);
        float s2 = (float)exp((double)sv2 - m);
        float s3 = (float)exp((double)sv3 - m);
        float s4 = (float)exp((double)sv4 - m);
        float s5 = (float)exp((double)sv5 - m);
        float s6 = (float)exp((double)sv6 - m);
        float s7 = (float)exp((double)sv7 - m);
        float s8 = (float)exp((double)sv8 - m);
        float s9 = (float)exp((double)sv9 - m);

#define TIESWAP(CA, IA, CB, IB)                           \
    {                                                     \
        bool sw = (CA == CB) && (IA > IB);                \
        int tt = IA;                                      \
        IA = sw ? IB : IA;                                \
        IB = sw ? tt : IB;                                \
    }
#define TIEPASS                                           \
    TIESWAP(s0, si0, s1, si1)                             \
    TIESWAP(s1, si1, s2, si2)                             \
    TIESWAP(s2, si2, s3, si3)                             \
    TIESWAP(s3, si3, s4, si4)                             \
    TIESWAP(s4, si4, s5, si5)                             \
    TIESWAP(s5, si5, s6, si6)                             \
    TIESWAP(s6, si6, s7, si7)                             \
    TIESWAP(s7, si7, s8, si8)                             \
    TIESWAP(s8, si8, s9, si9)

        TIEPASS
        TIEPASS
        TIEPASS
        TIEPASS

        ce0 = s0; ce1 = s1; ce2 = s2; ce3 = s3;
        ce4 = s4; ce5 = s5; ce6 = s6; ce7 = s7;
        o0 = si0; o1 = si1; o2 = si2; o3 = si3;
        o4 = si4; o5 = si5; o6 = si6; o7 = si7;
    }

    float s = ((ce0 + ce1) + (ce2 + ce3)) + ((ce4 + ce5) + (ce6 + ce7));
    float r = 1.0f / s;

    // ---- each lane stores ONE float4, selected by its quarter q:
    //   q=0 -> weights[0:4], q=1 -> weights[4:8], q=2 -> ids[0:4], q=3 -> ids[4:8]
    // wave footprint: 512B contiguous in w_out + 512B contiguous in id_out.
    const bool hi  = (q & 1);
    const bool typ = (q >> 1);      // 0 = weights, 1 = ids

    float4 outv;
    outv.x = typ ? (hi ? (float)o4 : (float)o0) : (hi ? ce4 * r : ce0 * r);
    outv.y = typ ? (hi ? (float)o5 : (float)o1) : (hi ? ce5 * r : ce1 * r);
    outv.z = typ ? (hi ? (float)o6 : (float)o2) : (hi ? ce6 * r : ce2 * r);
    outv.w = typ ? (hi ? (float)o7 : (float)o3) : (hi ? ce7 * r : ce3 * r);

    float* basep = typ ? id_out : w_out;
    float4* op = (float4*)(basep + (size_t)row * TOPK) + (hi ? 1 : 0);
    *op = outv;
}

extern "C" void kernel_launch(void* const* d_in, const int* in_sizes, int n_in,
                              void* d_out, int out_size, void* d_ws, size_t ws_size,
                              hipStream_t stream) {
    const float* logits = (const float*)d_in[0];
    int nrows = in_sizes[0] / NEXP;

    float* out    = (float*)d_out;
    float* w_out  = out;
    float* id_out = out + (size_t)nrows * TOPK;
    float* l_out  = out + (size_t)nrows * 2 * TOPK;

    // 64 rows per block (4 waves x 16 rows), 256 threads
    int blocks = (nrows + 63) / 64;
    topk_router_kernel<<<blocks, 256, 0, stream>>>(logits, w_out, id_out, l_out, nrows);
}

// Round 13
// 124.900 us; speedup vs baseline: 2.0401x; 2.0401x over previous
//
#include <hip/hip_runtime.h>
#include <hip/hip_bf16.h>
#include <math.h>

#define NEXP 64
#define TOPK 8

// 4 lanes per row, 16 rows per wave, 4 independent waves per block.
// No LDS, no barriers, no transpose. Ownership mapping: lane (r,q)'s i-th
// float4 chunk = element range [i*16 + q*4, i*16 + q*4 + 4) -> per load/store
// instruction a quad covers a CONTIGUOUS 64B (2x fewer line-touches than the
// q*16+i*4 mapping). Selection = Batcher sort-8 x2 + bitonic top-8 merges,
// cross-lane via __shfl_xor masks 1/2 (intra-quad -> DPP).
__global__ __launch_bounds__(256) void topk_router_kernel(
    const float* __restrict__ logits,
    float* __restrict__ w_out,      // [N,8] weights
    float* __restrict__ id_out,     // [N,8] ids stored as float values
    float* __restrict__ l_out,      // [N,64] passthrough copy
    int nrows)
{
    const int lane = threadIdx.x & 63;
    const int wv   = threadIdx.x >> 6;
    const int q    = lane & 3;          // quarter-slot of the row this lane owns
    const int rloc = lane >> 2;         // row within wave 0..15
    const int row  = (blockIdx.x * 4 + wv) * 16 + rloc;
    if (row >= nrows) return;           // whole 4-lane quads exit together

    // chunk i of this lane: float4 index row*16 + i*4 + q
    const float4* __restrict__ src = (const float4*)logits + (size_t)row * (NEXP / 4) + q;
    float4* __restrict__ dst       = (float4*)l_out  + (size_t)row * (NEXP / 4) + q;

    float4 a0 = src[0], a1 = src[4], a2 = src[8], a3 = src[12];
    dst[0] = a0; dst[4] = a1; dst[8] = a2; dst[12] = a3;

    // element indices: chunk i covers i*16 + q*4 + {0,1,2,3}
    const int b0 = q * 4;
    float e0 = a0.x,  e1 = a0.y,  e2 = a0.z,  e3 = a0.w;
    float e4 = a1.x,  e5 = a1.y,  e6 = a1.z,  e7 = a1.w;
    float e8 = a2.x,  e9 = a2.y,  e10 = a2.z, e11 = a2.w;
    float e12 = a3.x, e13 = a3.y, e14 = a3.z, e15 = a3.w;
    int i0 = b0 + 0,       i1 = b0 + 1,       i2 = b0 + 2,       i3 = b0 + 3;
    int i4 = 16 + b0 + 0,  i5 = 16 + b0 + 1,  i6 = 16 + b0 + 2,  i7 = 16 + b0 + 3;
    int i8 = 32 + b0 + 0,  i9 = 32 + b0 + 1,  i10 = 32 + b0 + 2, i11 = 32 + b0 + 3;
    int i12 = 48 + b0 + 0, i13 = 48 + b0 + 1, i14 = 48 + b0 + 2, i15 = 48 + b0 + 3;

    float rm = -INFINITY;    // max of all rejected elements

    // compare-exchange, descending, strict (> only): equal values never swap
#define CE(VA, IA, VB, IB)                                        \
    {                                                             \
        bool s_ = ((VB) > (VA));                                  \
        float tv_ = (VA); int ti_ = (IA);                         \
        VA = s_ ? (VB) : (VA); IA = s_ ? (IB) : (IA);             \
        VB = s_ ? tv_  : (VB); IB = s_ ? ti_  : (IB);             \
    }

    // Batcher odd-even merge sort for 8 (19 CE), descending
#define SORT8(V0,I0,V1,I1,V2,I2,V3,I3,V4,I4,V5,I5,V6,I6,V7,I7)        \
    CE(V0,I0,V1,I1) CE(V2,I2,V3,I3) CE(V4,I4,V5,I5) CE(V6,I6,V7,I7)   \
    CE(V0,I0,V2,I2) CE(V1,I1,V3,I3) CE(V4,I4,V6,I6) CE(V5,I5,V7,I7)   \
    CE(V1,I1,V2,I2) CE(V5,I5,V6,I6)                                   \
    CE(V0,I0,V4,I4) CE(V1,I1,V5,I5) CE(V2,I2,V6,I6) CE(V3,I3,V7,I7)   \
    CE(V2,I2,V4,I4) CE(V3,I3,V5,I5)                                   \
    CE(V1,I1,V2,I2) CE(V3,I3,V4,I4) CE(V5,I5,V6,I6)

    SORT8(e0,i0, e1,i1, e2,i2, e3,i3, e4,i4, e5,i5, e6,i6, e7,i7)
    SORT8(e8,i8, e9,i9, e10,i10, e11,i11, e12,i12, e13,i13, e14,i14, e15,i15)

    // winner/loser step: VA <- max(VA,VB), rm <- max(rm, loser)
#define MTOP(VA, IA, VB, IB)                                      \
    {                                                             \
        bool s_ = ((VB) > (VA));                                  \
        float lo_ = s_ ? (VA) : (VB);                             \
        VA = s_ ? (VB) : (VA); IA = s_ ? (IB) : (IA);             \
        rm = fmaxf(rm, lo_);                                      \
    }

    // bitonic clean of a descending-bitonic 8 (12 CE)
#define BITONIC8(V0,I0,V1,I1,V2,I2,V3,I3,V4,I4,V5,I5,V6,I6,V7,I7)     \
    CE(V0,I0,V4,I4) CE(V1,I1,V5,I5) CE(V2,I2,V6,I6) CE(V3,I3,V7,I7)   \
    CE(V0,I0,V2,I2) CE(V1,I1,V3,I3) CE(V4,I4,V6,I6) CE(V5,I5,V7,I7)   \
    CE(V0,I0,V1,I1) CE(V2,I2,V3,I3) CE(V4,I4,V5,I5) CE(V6,I6,V7,I7)

    // intra-lane: top-8 of two sorted-8 lists (bitonic merge)
    MTOP(e0,i0, e15,i15) MTOP(e1,i1, e14,i14)
    MTOP(e2,i2, e13,i13) MTOP(e3,i3, e12,i12)
    MTOP(e4,i4, e11,i11) MTOP(e5,i5, e10,i10)
    MTOP(e6,i6, e9,i9)   MTOP(e7,i7, e8,i8)
    BITONIC8(e0,i0, e1,i1, e2,i2, e3,i3, e4,i4, e5,i5, e6,i6, e7,i7)

    // cross-lane merge: partner's sorted-8 reversed feeds the bitonic merge
#define MERGE_LEVEL(MASK)                                                     \
    {                                                                         \
        float b0_ = __shfl_xor(e0, MASK), b1_ = __shfl_xor(e1, MASK);         \
        float b2_ = __shfl_xor(e2, MASK), b3_ = __shfl_xor(e3, MASK);         \
        float b4_ = __shfl_xor(e4, MASK), b5_ = __shfl_xor(e5, MASK);         \
        float b6_ = __shfl_xor(e6, MASK), b7_ = __shfl_xor(e7, MASK);         \
        int   j0_ = __shfl_xor(i0, MASK), j1_ = __shfl_xor(i1, MASK);         \
        int   j2_ = __shfl_xor(i2, MASK), j3_ = __shfl_xor(i3, MASK);         \
        int   j4_ = __shfl_xor(i4, MASK), j5_ = __shfl_xor(i5, MASK);         \
        int   j6_ = __shfl_xor(i6, MASK), j7_ = __shfl_xor(i7, MASK);         \
        float pr_ = __shfl_xor(rm, MASK);                                     \
        rm = fmaxf(rm, pr_);                                                  \
        MTOP(e0,i0, b7_,j7_) MTOP(e1,i1, b6_,j6_)                             \
        MTOP(e2,i2, b5_,j5_) MTOP(e3,i3, b4_,j4_)                             \
        MTOP(e4,i4, b3_,j3_) MTOP(e5,i5, b2_,j2_)                             \
        MTOP(e6,i6, b1_,j1_) MTOP(e7,i7, b0_,j0_)                             \
        BITONIC8(e0,i0, e1,i1, e2,i2, e3,i3, e4,i4, e5,i5, e6,i6, e7,i7)      \
    }

    MERGE_LEVEL(1)
    MERGE_LEVEL(2)

    // ---- tie screen: any equality/near-tie involving a selected element or
    // the 8/9 boundary lands adjacent here (lists are sorted); gap<=T -> slow.
    const float T = 1e-6f;
    bool tie = ((e0 - e1) <= T) | ((e1 - e2) <= T) | ((e2 - e3) <= T) |
               ((e3 - e4) <= T) | ((e4 - e5) <= T) | ((e5 - e6) <= T) |
               ((e6 - e7) <= T) | ((e7 - rm) <= T);

    float ce0, ce1, ce2, ce3, ce4, ce5, ce6, ce7;
    int   o0, o1, o2, o3, o4, o5, o6, o7;

    if (__builtin_expect(!tie, 1)) {
        // fast path: no representable score tie possible
        ce0 = 1.0f;
        ce1 = __expf(e1 - e0); ce2 = __expf(e2 - e0);
        ce3 = __expf(e3 - e0); ce4 = __expf(e4 - e0);
        ce5 = __expf(e5 - e0); ce6 = __expf(e6 - e0);
        ce7 = __expf(e7 - e0);
        o0 = i0; o1 = i1; o2 = i2; o3 = i3;
        o4 = i4; o5 = i5; o6 = i6; o7 = i7;
    } else {
        // exact path (rare, exec-masked, deterministic per row): re-read the
        // row, depth-10 stable selection + correctly-rounded-exp tie order.
        const float* rowp = logits + (size_t)row * NEXP;
        float sv0 = -INFINITY, sv1 = -INFINITY, sv2 = -INFINITY, sv3 = -INFINITY;
        float sv4 = -INFINITY, sv5 = -INFINITY, sv6 = -INFINITY, sv7 = -INFINITY;
        float sv8 = -INFINITY, sv9 = -INFINITY;
        int   si0 = 0, si1 = 0, si2 = 0, si3 = 0, si4 = 0;
        int   si5 = 0, si6 = 0, si7 = 0, si8 = 0, si9 = 0;

#define SLOW_STAGE(TV, TI)                                \
    {                                                     \
        bool gt = (x > TV);                               \
        float nv = gt ? x  : TV;                          \
        float cv = gt ? TV : x;                           \
        int   ni = gt ? xi : TI;                          \
        int   ci = gt ? TI : xi;                          \
        TV = nv; x = cv; TI = ni; xi = ci;                \
    }

        #pragma unroll 1
        for (int e = 0; e < NEXP; ++e) {
            float x = rowp[e]; int xi = e;
            SLOW_STAGE(sv0, si0)
            SLOW_STAGE(sv1, si1)
            SLOW_STAGE(sv2, si2)
            SLOW_STAGE(sv3, si3)
            SLOW_STAGE(sv4, si4)
            SLOW_STAGE(sv5, si5)
            SLOW_STAGE(sv6, si6)
            SLOW_STAGE(sv7, si7)
            SLOW_STAGE(sv8, si8)
            SLOW_STAGE(sv9, si9)
        }

        double m = (double)sv0;
        float s0 = (float)exp((double)sv0 - m);
        float s1 = (float)exp((double)sv1 - m);
        float s2 = (float)exp((double)sv2 - m);
        float s3 = (float)exp((double)sv3 - m);
        float s4 = (float)exp((double)sv4 - m);
        float s5 = (float)exp((double)sv5 - m);
        float s6 = (float)exp((double)sv6 - m);
        float s7 = (float)exp((double)sv7 - m);
        float s8 = (float)exp((double)sv8 - m);
        float s9 = (float)exp((double)sv9 - m);

#define TIESWAP(CA, IA, CB, IB)                           \
    {                                                     \
        bool sw = (CA == CB) && (IA > IB);                \
        int tt = IA;                                      \
        IA = sw ? IB : IA;                                \
        IB = sw ? tt : IB;                                \
    }
#define TIEPASS                                           \
    TIESWAP(s0, si0, s1, si1)                             \
    TIESWAP(s1, si1, s2, si2)                             \
    TIESWAP(s2, si2, s3, si3)                             \
    TIESWAP(s3, si3, s4, si4)                             \
    TIESWAP(s4, si4, s5, si5)                             \
    TIESWAP(s5, si5, s6, si6)                             \
    TIESWAP(s6, si6, s7, si7)                             \
    TIESWAP(s7, si7, s8, si8)                             \
    TIESWAP(s8, si8, s9, si9)

        TIEPASS
        TIEPASS
        TIEPASS
        TIEPASS

        ce0 = s0; ce1 = s1; ce2 = s2; ce3 = s3;
        ce4 = s4; ce5 = s5; ce6 = s6; ce7 = s7;
        o0 = si0; o1 = si1; o2 = si2; o3 = si3;
        o4 = si4; o5 = si5; o6 = si6; o7 = si7;
    }

    float s = ((ce0 + ce1) + (ce2 + ce3)) + ((ce4 + ce5) + (ce6 + ce7));
    float r = 1.0f / s;

    // ---- each lane stores ONE float4, selected by its quarter-slot q:
    //   q=0 -> weights[0:4], q=1 -> weights[4:8], q=2 -> ids[0:4], q=3 -> ids[4:8]
    // wave footprint: 512B contiguous in w_out + 512B contiguous in id_out.
    const bool hi  = (q & 1);
    const bool typ = (q >> 1);      // 0 = weights, 1 = ids

    float4 outv;
    outv.x = typ ? (hi ? (float)o4 : (float)o0) : (hi ? ce4 * r : ce0 * r);
    outv.y = typ ? (hi ? (float)o5 : (float)o1) : (hi ? ce5 * r : ce1 * r);
    outv.z = typ ? (hi ? (float)o6 : (float)o2) : (hi ? ce6 * r : ce2 * r);
    outv.w = typ ? (hi ? (float)o7 : (float)o3) : (hi ? ce7 * r : ce3 * r);

    float* basep = typ ? id_out : w_out;
    float4* op = (float4*)(basep + (size_t)row * TOPK) + (hi ? 1 : 0);
    *op = outv;
}

extern "C" void kernel_launch(void* const* d_in, const int* in_sizes, int n_in,
                              void* d_out, int out_size, void* d_ws, size_t ws_size,
                              hipStream_t stream) {
    const float* logits = (const float*)d_in[0];
    int nrows = in_sizes[0] / NEXP;

    float* out    = (float*)d_out;
    float* w_out  = out;
    float* id_out = out + (size_t)nrows * TOPK;
    float* l_out  = out + (size_t)nrows * 2 * TOPK;

    // 64 rows per block (4 waves x 16 rows), 256 threads
    int blocks = (nrows + 63) / 64;
    topk_router_kernel<<<blocks, 256, 0, stream>>>(logits, w_out, id_out, l_out, nrows);
}